// Round 8
// baseline (272.932 us; speedup 1.0000x reference)
//
#include <hip/hip_runtime.h>
#include <stdint.h>

#define HIDDEN 512
#define NLAYERS 3
#define KNN 8
#define CAP 64
#define NBMAX (KNN + CAP)   // combined fwd+rev neighbor list stride
#define EPSV 1e-5f
#define GRID 32
#define NCELL (GRID * GRID)

typedef unsigned long long u64;
typedef __attribute__((ext_vector_type(8))) short short8;   // 8 bf16 = 4 VGPRs
typedef __attribute__((ext_vector_type(4))) float f32x4;    // MFMA acc

// async global->LDS DMA, 16 B/lane; LDS dest = wave-uniform base + lane*16
#define GLL16(gp, lp)                                                         \
  __builtin_amdgcn_global_load_lds(                                           \
      (const __attribute__((address_space(1))) unsigned int*)(gp),            \
      (__attribute__((address_space(3))) unsigned int*)(lp), 16, 0, 0)

__device__ inline unsigned short f2bf(float x) {  // RNE fp32 -> bf16 bits
  union { float f; unsigned u; } v; v.f = x;
  unsigned r = v.u + 0x7FFFu + ((v.u >> 16) & 1u);
  return (unsigned short)(r >> 16);
}
__device__ inline float bf2f(unsigned short u) {
  return __uint_as_float((unsigned)u << 16);
}

// ---------------------------------------------------------------------------
// Grid build: one 1024-thread block per batch. Counting sort into 32x32 cells.
// Sorted order (scoord/sorig) is the processing order of the whole pipeline.
// ---------------------------------------------------------------------------
__global__ __launch_bounds__(1024) void grid_build_kernel(
    const float2* __restrict__ coords, int* __restrict__ cell_start,
    float2* __restrict__ scoord, int* __restrict__ sorig, int N) {
  __shared__ int hist[NCELL];
  __shared__ int offs[NCELL];
  int b = blockIdx.x;
  int t = threadIdx.x;
  hist[t] = 0;
  __syncthreads();
  const float2* cb = coords + (size_t)b * N;
  int mycell[4];
#pragma unroll
  for (int r = 0; r < 4; ++r) {
    int i = t + r * 1024;
    float2 c = cb[i];
    int cx = (int)(c.x * GRID); cx = cx < 0 ? 0 : (cx > GRID - 1 ? GRID - 1 : cx);
    int cy = (int)(c.y * GRID); cy = cy < 0 ? 0 : (cy > GRID - 1 ? GRID - 1 : cy);
    mycell[r] = cy * GRID + cx;
    atomicAdd(&hist[mycell[r]], 1);
  }
  __syncthreads();
  int v = hist[t];
  offs[t] = v;
  __syncthreads();
  for (int d = 1; d < NCELL; d <<= 1) {
    int add = (t >= d) ? offs[t - d] : 0;
    __syncthreads();
    offs[t] += add;
    __syncthreads();
  }
  int excl = offs[t] - v;
  cell_start[(size_t)b * (NCELL + 1) + t] = excl;
  if (t == 0) cell_start[(size_t)b * (NCELL + 1) + NCELL] = N;
  hist[t] = excl;
  __syncthreads();
#pragma unroll
  for (int r = 0; r < 4; ++r) {
    int i = t + r * 1024;
    int pos = atomicAdd(&hist[mycell[r]], 1);
    scoord[(size_t)b * N + pos] = cb[i];
    sorig[(size_t)b * N + pos] = i;
  }
}

// ---------------------------------------------------------------------------
// Gang-of-8 grid kNN (checker-bit-exact d2) with the reverse-adjacency build
// fused into the merge loop (owner lane atomics).
// ---------------------------------------------------------------------------
__global__ __launch_bounds__(256) void knn_grid_kernel(
    const int* __restrict__ cell_start, const float2* __restrict__ scoord,
    const int* __restrict__ sorig, int* __restrict__ knn_s,
    int* __restrict__ cnt, int* __restrict__ rev, int N, int BN) {
  int gang = (blockIdx.x * blockDim.x + threadIdx.x) >> 3;
  int sub = threadIdx.x & 7;
  if (gang >= BN) return;
  int b = gang / N;
  float2 cn = scoord[gang];
  float sqn = __fmaf_rn(cn.y, cn.y, __fmul_rn(cn.x, cn.x));
  int cx = (int)(cn.x * GRID); cx = cx < 0 ? 0 : (cx > GRID - 1 ? GRID - 1 : cx);
  int cy = (int)(cn.y * GRID); cy = cy < 0 ? 0 : (cy > GRID - 1 ? GRID - 1 : cy);
  const int* cs = cell_start + (size_t)b * (NCELL + 1);
  const float2* sc = scoord + (size_t)b * N;
  const int* so = sorig + (size_t)b * N;

  u64 list[KNN + 1];
#pragma unroll
  for (int j = 0; j <= KNN; ++j) list[j] = ~0ull;

  auto scan_cell = [&](int ux, int uy) {
    int c = uy * GRID + ux;
    int s = cs[c], e = cs[c + 1];
    for (int p = s + sub; p < e; p += 8) {
      float2 cm = sc[p];
      float sqm = __fmaf_rn(cm.y, cm.y, __fmul_rn(cm.x, cm.x));
      float dot = __fmaf_rn(cn.y, cm.y, __fmul_rn(cn.x, cm.x));
      float d2 = __fsub_rn(__fadd_rn(sqn, sqm), __fmul_rn(2.0f, dot));
      unsigned ub = __float_as_uint(d2);
      unsigned k32 = (ub & 0x80000000u) ? ~ub : (ub | 0x80000000u);
      u64 key = ((u64)k32 << 24) | ((u64)(unsigned)so[p] << 12) | (u64)(unsigned)p;
      if (key < list[KNN]) {
        u64 cur = key;
#pragma unroll
        for (int j = 0; j <= KNN; ++j) {
          u64 lo = list[j] < cur ? list[j] : cur;
          u64 hi = list[j] < cur ? cur : list[j];
          list[j] = lo;
          cur = hi;
        }
      }
    }
  };

  for (int q = 0; q <= GRID; ++q) {
    if (q == 0) {
      scan_cell(cx, cy);
    } else {
      int x0 = cx - q, x1 = cx + q, y0 = cy - q, y1 = cy + q;
      int xa = x0 < 0 ? 0 : x0, xb_ = x1 > GRID - 1 ? GRID - 1 : x1;
      for (int ux = xa; ux <= xb_; ++ux) {
        if (y0 >= 0) scan_cell(ux, y0);
        if (y1 <= GRID - 1) scan_cell(ux, y1);
      }
      int ya = (y0 + 1) < 0 ? 0 : y0 + 1, yb = (y1 - 1) > GRID - 1 ? GRID - 1 : y1 - 1;
      for (int uy = ya; uy <= yb; ++uy) {
        if (x0 >= 0) scan_cell(x0, uy);
        if (x1 <= GRID - 1) scan_cell(x1, uy);
      }
      float bound = (float)q * (1.0f / GRID);
      float thr = bound * bound - 1e-5f;
      int cntn = 0;
#pragma unroll
      for (int j = 0; j <= KNN; ++j) {
        unsigned k32 = (unsigned)(list[j] >> 24);
        float d2v = (k32 >= 0x80000000u) ? __uint_as_float(k32 & 0x7FFFFFFFu)
                                         : -__uint_as_float(~k32);
        cntn += (list[j] != ~0ull && d2v < thr) ? 1 : 0;
      }
#pragma unroll
      for (int o = 1; o < 8; o <<= 1) cntn += __shfl_xor(cntn, o, 64);
      if (cntn >= 9) break;
    }
  }

  int gl = gang - b * N;  // local sorted index of this node
  for (int r = 0; r <= KNN; ++r) {
    u64 cand = list[0];
    u64 mn = cand;
#pragma unroll
    for (int o = 1; o < 8; o <<= 1) {
      u64 v = __shfl_xor(mn, o, 64);
      mn = v < mn ? v : mn;
    }
    if (cand == mn) {
#pragma unroll
      for (int j = 0; j < KNN; ++j) list[j] = list[j + 1];
      list[KNN] = ~0ull;
      if (r > 0) {
        int m = (int)(mn & 0xFFFull);  // sorted-space neighbor
        knn_s[(size_t)gang * KNN + (r - 1)] = m;
        int gm = b * N + m;
        int pos = atomicAdd(&cnt[gm], 1);
        if (pos < CAP) rev[(size_t)gm * CAP + pos] = gl;
      }
    }
  }
}

// ---------------------------------------------------------------------------
// One-time combined neighbor list build: nlist[bn] = knn fwd (order kept) ++
// rev entries minus dups (order kept). Accumulation order in agg stays the
// old fwd-then-rev-dedup order (bit-identical), dedup runs once per session.
// ---------------------------------------------------------------------------
__global__ __launch_bounds__(256) void nbr_build_kernel(
    const int* __restrict__ knn, const int* __restrict__ cnt,
    const int* __restrict__ rev, int* __restrict__ nlist,
    int* __restrict__ nlcnt, int BN) {
  int bn = blockIdx.x * blockDim.x + threadIdx.x;
  if (bn >= BN) return;
  const int* my = knn + (size_t)bn * KNN;
  int* ol = nlist + (size_t)bn * NBMAX;
  int nb[KNN];
#pragma unroll
  for (int j = 0; j < KNN; ++j) { nb[j] = my[j]; ol[j] = nb[j]; }
  int m = KNN;
  int indeg = cnt[bn];
  if (indeg > CAP) indeg = CAP;
  const int* rv = rev + (size_t)bn * CAP;
  for (int i = 0; i < indeg; ++i) {
    int r = rv[i];
    bool dup = false;
#pragma unroll
    for (int j = 0; j < KNN; ++j) dup = dup || (r == nb[j]);
    if (!dup) ol[m++] = r;
  }
  nlcnt[bn] = m;
}

// ---------------------------------------------------------------------------
// Aggregation in sorted space: branch-free gather-sum over nlist.
// One WAVE per row (16 B/lane short8 loads), 256-thread blocks = 4 rows.
// XCD-aware block swizzle (T1): XCD k owns a contiguous 2048-row chunk
// (2 MB + halo -> L2-resident gather). Per-element accumulation order is
// unchanged (sequential over nlist) -> bit-identical output.
// ---------------------------------------------------------------------------
__global__ __launch_bounds__(256) void agg_kernel(const unsigned short* __restrict__ x,
                                                  const int* __restrict__ nlist,
                                                  const int* __restrict__ nlcnt,
                                                  unsigned short* __restrict__ aggb,
                                                  int N) {
  int bid = blockIdx.x;
  int nwg = gridDim.x;                       // BN/4, divisible by 8
  int blk = ((nwg & 7) == 0) ? ((bid & 7) * (nwg >> 3) + (bid >> 3)) : bid;
  int w = threadIdx.x >> 6, lane = threadIdx.x & 63;
  int bn = blk * 4 + w;                      // row this wave owns
  int b = bn / N;
  int m = nlcnt[bn];
  const int* nl = nlist + (size_t)bn * NBMAX;
  const unsigned short* xb = x + (size_t)b * N * HIDDEN + lane * 8;
  float acc[8] = {0.f, 0.f, 0.f, 0.f, 0.f, 0.f, 0.f, 0.f};
  int i = 0;
  for (; i + 4 <= m; i += 4) {
    int r0 = nl[i], r1 = nl[i + 1], r2 = nl[i + 2], r3 = nl[i + 3];
    short8 v0 = *(const short8*)(xb + (size_t)r0 * HIDDEN);
    short8 v1 = *(const short8*)(xb + (size_t)r1 * HIDDEN);
    short8 v2 = *(const short8*)(xb + (size_t)r2 * HIDDEN);
    short8 v3 = *(const short8*)(xb + (size_t)r3 * HIDDEN);
#pragma unroll
    for (int e = 0; e < 8; ++e) acc[e] += bf2f((unsigned short)v0[e]);
#pragma unroll
    for (int e = 0; e < 8; ++e) acc[e] += bf2f((unsigned short)v1[e]);
#pragma unroll
    for (int e = 0; e < 8; ++e) acc[e] += bf2f((unsigned short)v2[e]);
#pragma unroll
    for (int e = 0; e < 8; ++e) acc[e] += bf2f((unsigned short)v3[e]);
  }
  for (; i < m; ++i) {
    short8 v = *(const short8*)(xb + (size_t)nl[i] * HIDDEN);
#pragma unroll
    for (int e = 0; e < 8; ++e) acc[e] += bf2f((unsigned short)v[e]);
  }
  short8 o;
#pragma unroll
  for (int e = 0; e < 8; ++e) o[e] = (short)f2bf(acc[e]);
  *(short8*)(aggb + (size_t)bn * HIDDEN + lane * 8) = o;
}

// ---------------------------------------------------------------------------
// Initial features -> bf16, permuted to sorted order.
// ---------------------------------------------------------------------------
__global__ __launch_bounds__(128) void x2bf_perm_kernel(const float* __restrict__ x,
                                                        const int* __restrict__ sorig,
                                                        unsigned short* __restrict__ xs,
                                                        int N) {
  int row = blockIdx.x;
  int b = row / N;
  int src = b * N + sorig[row];
  int t = threadIdx.x;
  float4 v = ((const float4*)(x + (size_t)src * HIDDEN))[t];
  ushort4 o;
  o.x = f2bf(v.x); o.y = f2bf(v.y); o.z = f2bf(v.z); o.w = f2bf(v.w);
  ((ushort4*)(xs + (size_t)row * HIDDEN))[t] = o;
}

// ---------------------------------------------------------------------------
// W convert+transpose: W[l][k][n] fp32 -> Wt[l][n][k] bf16.
// ---------------------------------------------------------------------------
__global__ __launch_bounds__(256) void wconv_kernel(const float* __restrict__ W,
                                                    unsigned short* __restrict__ Wt) {
  __shared__ unsigned short tile[64][65];
  int l = blockIdx.x >> 6;
  int t6 = blockIdx.x & 63;
  int k0 = (t6 >> 3) * 64, n0 = (t6 & 7) * 64;
  const float* Wl = W + (size_t)l * HIDDEN * HIDDEN;
  unsigned short* Wtl = Wt + (size_t)l * HIDDEN * HIDDEN;
  int t = threadIdx.x;
#pragma unroll
  for (int r = 0; r < 4; ++r) {
    int row = (t >> 4) + r * 16;
    int col = (t & 15) * 4;
    float4 v = *(const float4*)(Wl + (size_t)(k0 + row) * HIDDEN + n0 + col);
    tile[col + 0][row] = f2bf(v.x);
    tile[col + 1][row] = f2bf(v.y);
    tile[col + 2][row] = f2bf(v.z);
    tile[col + 3][row] = f2bf(v.w);
  }
  __syncthreads();
#pragma unroll
  for (int r = 0; r < 4; ++r) {
    int row = (t >> 4) + r * 16;
    int col = (t & 15) * 4;
    ushort4 o;
    o.x = tile[row][col + 0]; o.y = tile[row][col + 1];
    o.z = tile[row][col + 2]; o.w = tile[row][col + 3];
    *(ushort4*)(Wtl + (size_t)(n0 + row) * HIDDEN + k0 + col) = o;
  }
}

// ---------------------------------------------------------------------------
// bf16 MFMA GEMM: tmpb = bf16(A @ W + bias). 128x128 tile, BK=32, 4 waves 2x2.
// T3-minimum 2-phase double-buffer (round-7): prefetch next K-tile's
// global_load_lds BEFORE computing the current tile, one barrier per iter.
// NEW (round-8): C-write staged through padded LDS tile. The direct MFMA-
// layout store was 64 global_store_short per wave at ~32B effective burst
// (lm-group = 16 consecutive bf16 = 32B; q-groups on 4 different rows).
// Now: bf16(acc+bias) -> Ct[128][132] (stride 132 => the 4 q-group rows are
// 1056B apart = 8-bank shift => disjoint bank octets, conflict-free b16
// writes), barrier, then 16B/lane short8 global stores, fully coalesced
// (1KB per wave instruction). Same values, same addresses -> bit-identical.
// LDS 32KB(dbuf)+33KB(Ct) = 65KB; grid 512 = 2 blocks/CU anyway.
// ---------------------------------------------------------------------------
#define CT_STRIDE 132
__global__ __launch_bounds__(256) void gemm_mfma_kernel(
    const unsigned short* __restrict__ A,
    const unsigned short* __restrict__ Wt,
    const float* __restrict__ bias,
    unsigned short* __restrict__ Cb) {
  __shared__ unsigned short As[2][128 * 32];
  __shared__ unsigned short Bs[2][128 * 32];
  __shared__ unsigned short Ct[128 * CT_STRIDE];
  int t = threadIdx.x;
  int bid = blockIdx.x;
  int sw = (bid & 7) * 64 + (bid >> 3);
  int m0 = (sw >> 2) * 128;
  int n0 = (sw & 3) * 128;
  int w = t >> 6, lane = t & 63;
  int wr = w >> 1, wc = w & 1;
  int lm = lane & 15, q = lane >> 4;

  f32x4 acc[4][4];
#pragma unroll
  for (int i = 0; i < 4; ++i)
#pragma unroll
    for (int j = 0; j < 4; ++j) acc[i][j] = (f32x4){0.f, 0.f, 0.f, 0.f};

  int lrow = lane >> 2;        // 0..15 within a 16-row chunk
  int lcol = (lane & 3) * 8;   // 0,8,16,24
  int e0 = w, e1 = w + 4;      // chunk ids this wave stages

  const unsigned short* Arow0 = A + (size_t)(m0 + e0 * 16 + lrow) * HIDDEN + lcol;
  const unsigned short* Arow1 = A + (size_t)(m0 + e1 * 16 + lrow) * HIDDEN + lcol;
  const unsigned short* Brow0 = Wt + (size_t)(n0 + e0 * 16 + lrow) * HIDDEN + lcol;
  const unsigned short* Brow1 = Wt + (size_t)(n0 + e1 * 16 + lrow) * HIDDEN + lcol;

  // prologue: stage K-tile 0 into buffer 0
  GLL16(Arow0, As[0] + e0 * 512);
  GLL16(Arow1, As[0] + e1 * 512);
  GLL16(Brow0, Bs[0] + e0 * 512);
  GLL16(Brow1, Bs[0] + e1 * 512);
  __syncthreads();  // implicit vmcnt(0): tile 0 resident

  int cur = 0;
  for (int k0 = 0; k0 < HIDDEN; k0 += 32) {
    int nxt = cur ^ 1;
    if (k0 + 32 < HIDDEN) {   // prefetch next K-tile into the other buffer
      GLL16(Arow0 + k0 + 32, As[nxt] + e0 * 512);
      GLL16(Arow1 + k0 + 32, As[nxt] + e1 * 512);
      GLL16(Brow0 + k0 + 32, Bs[nxt] + e0 * 512);
      GLL16(Brow1 + k0 + 32, Bs[nxt] + e1 * 512);
    }
    short8 af[4], bfr[4];
#pragma unroll
    for (int i = 0; i < 4; ++i)
      af[i] = *(const short8*)(As[cur] + (wr * 64 + i * 16 + lm) * 32 + q * 8);
#pragma unroll
    for (int j = 0; j < 4; ++j)
      bfr[j] = *(const short8*)(Bs[cur] + (wc * 64 + j * 16 + lm) * 32 + q * 8);
#pragma unroll
    for (int i = 0; i < 4; ++i)
#pragma unroll
      for (int j = 0; j < 4; ++j)
        acc[i][j] = __builtin_amdgcn_mfma_f32_16x16x32_bf16(af[i], bfr[j], acc[i][j], 0, 0, 0);
    __syncthreads();  // vmcnt(0)+lgkmcnt(0): prefetch resident, reads done
    cur = nxt;
  }

  // ---- epilogue: round to LDS tile, then coalesced 16B stores.
#pragma unroll
  for (int i = 0; i < 4; ++i) {
#pragma unroll
    for (int j = 0; j < 4; ++j) {
      int col = wc * 64 + j * 16 + lm;
      float bv = bias[n0 + col];
#pragma unroll
      for (int r = 0; r < 4; ++r)
        Ct[(wr * 64 + i * 16 + q * 4 + r) * CT_STRIDE + col] =
            f2bf(acc[i][j][r] + bv);
    }
  }
  __syncthreads();
  int tr = t >> 4;          // 0..15: row within each 16-row group
  int tc = (t & 15) * 8;    // col octet
#pragma unroll
  for (int rr = 0; rr < 8; ++rr) {
    int row = rr * 16 + tr;
    short8 vv = *(const short8*)(Ct + row * CT_STRIDE + tc);
    *(short8*)(Cb + (size_t)(m0 + row) * HIDDEN + n0 + tc) = vv;
  }
}

// ---------------------------------------------------------------------------
// LayerNorm + ReLU + residual, sorted space, bf16 tmp input. One wave per row;
// lane owns elements 8*lane..8*lane+7. Stats in fp32.
// XCD chunk swizzle: XCD k processes rows 2048k..2048k+2047 — the same rows
// gemm wrote (tmpb) and agg/prev-ln wrote (xs) on XCD k -> reads L2-local.
// final=0: xs[row] = bf16(result). final=1: out[perm(row)] = fp32 result.
// ---------------------------------------------------------------------------
__global__ __launch_bounds__(256) void ln_relu_res_kernel(
    const unsigned short* __restrict__ tb, const float* __restrict__ g,
    const float* __restrict__ be, unsigned short* __restrict__ xs,
    float* __restrict__ out, const int* __restrict__ sorig,
    int N, int addres, int final_) {
  int bid = blockIdx.x;
  int nwg = gridDim.x;                       // BN/4 = 4096, divisible by 8
  int blk = ((nwg & 7) == 0) ? ((bid & 7) * (nwg >> 3) + (bid >> 3)) : bid;
  int row = (blk << 2) + (threadIdx.x >> 6);
  int lane = threadIdx.x & 63;
  uint4 u = ((const uint4*)(tb + (size_t)row * HIDDEN))[lane];
  float v[8];
  v[0] = bf2f((unsigned short)(u.x & 0xFFFFu)); v[1] = bf2f((unsigned short)(u.x >> 16));
  v[2] = bf2f((unsigned short)(u.y & 0xFFFFu)); v[3] = bf2f((unsigned short)(u.y >> 16));
  v[4] = bf2f((unsigned short)(u.z & 0xFFFFu)); v[5] = bf2f((unsigned short)(u.z >> 16));
  v[6] = bf2f((unsigned short)(u.w & 0xFFFFu)); v[7] = bf2f((unsigned short)(u.w >> 16));
  float s = 0.f, ss = 0.f;
#pragma unroll
  for (int k = 0; k < 8; ++k) { s += v[k]; ss += v[k] * v[k]; }
#pragma unroll
  for (int o = 32; o > 0; o >>= 1) {
    s += __shfl_xor(s, o, 64);
    ss += __shfl_xor(ss, o, 64);
  }
  float mu = s * (1.0f / HIDDEN);
  float var = ss * (1.0f / HIDDEN) - mu * mu;
  float inv = rsqrtf(var + EPSV);
  float4 g0 = ((const float4*)g)[2 * lane], g1 = ((const float4*)g)[2 * lane + 1];
  float4 b0 = ((const float4*)be)[2 * lane], b1 = ((const float4*)be)[2 * lane + 1];
  float gv[8] = {g0.x, g0.y, g0.z, g0.w, g1.x, g1.y, g1.z, g1.w};
  float bv[8] = {b0.x, b0.y, b0.z, b0.w, b1.x, b1.y, b1.z, b1.w};
  float o8[8];
#pragma unroll
  for (int k = 0; k < 8; ++k)
    o8[k] = fmaxf((v[k] - mu) * inv * gv[k] + bv[k], 0.f);
  ushort4* xrow = (ushort4*)(xs + (size_t)row * HIDDEN);
  if (addres) {
    ushort4 r0 = xrow[2 * lane], r1 = xrow[2 * lane + 1];
    o8[0] += bf2f(r0.x); o8[1] += bf2f(r0.y); o8[2] += bf2f(r0.z); o8[3] += bf2f(r0.w);
    o8[4] += bf2f(r1.x); o8[5] += bf2f(r1.y); o8[6] += bf2f(r1.z); o8[7] += bf2f(r1.w);
  }
  if (final_) {
    int b = row / N;
    size_t dst = (size_t)(b * N + sorig[row]) * HIDDEN;
    float4 w0 = {o8[0], o8[1], o8[2], o8[3]};
    float4 w1 = {o8[4], o8[5], o8[6], o8[7]};
    ((float4*)(out + dst))[2 * lane] = w0;
    ((float4*)(out + dst))[2 * lane + 1] = w1;
  } else {
    ushort4 q0, q1;
    q0.x = f2bf(o8[0]); q0.y = f2bf(o8[1]); q0.z = f2bf(o8[2]); q0.w = f2bf(o8[3]);
    q1.x = f2bf(o8[4]); q1.y = f2bf(o8[5]); q1.z = f2bf(o8[6]); q1.w = f2bf(o8[7]);
    xrow[2 * lane] = q0;
    xrow[2 * lane + 1] = q1;
  }
}

// ---------------------------------------------------------------------------
extern "C" void kernel_launch(void* const* d_in, const int* in_sizes, int n_in,
                              void* d_out, int out_size, void* d_ws, size_t ws_size,
                              hipStream_t stream) {
  const float* nf = (const float*)d_in[0];
  const float2* coords = (const float2*)d_in[1];
  const float* Wall = (const float*)d_in[2];
  const float* ball = (const float*)d_in[3];
  const float* gall = (const float*)d_in[4];
  const float* beall = (const float*)d_in[5];
  float* out = (float*)d_out;

  int BN = in_sizes[0] / HIDDEN;  // 16384
  int N = 4096;
  int B = BN / N;

  char* ws = (char*)d_ws;
  size_t off = 0;
  auto alloc = [&](size_t bytes) -> void* {
    off = (off + 255) & ~(size_t)255;
    void* p = ws + off;
    off += bytes;
    return p;
  };
  int* knn_s = (int*)alloc((size_t)BN * KNN * sizeof(int));
  int* cnt = (int*)alloc((size_t)BN * sizeof(int));
  int* rev = (int*)alloc((size_t)BN * CAP * sizeof(int));
  int* nlist = (int*)alloc((size_t)BN * NBMAX * sizeof(int));
  int* nlcnt = (int*)alloc((size_t)BN * sizeof(int));
  unsigned short* aggb = (unsigned short*)alloc((size_t)BN * HIDDEN * sizeof(unsigned short));
  unsigned short* tmpb = (unsigned short*)alloc((size_t)BN * HIDDEN * sizeof(unsigned short));
  unsigned short* Wt = (unsigned short*)alloc((size_t)NLAYERS * HIDDEN * HIDDEN * sizeof(unsigned short));
  unsigned short* xs = (unsigned short*)alloc((size_t)BN * HIDDEN * sizeof(unsigned short));
  int* cell_start = (int*)alloc((size_t)B * (NCELL + 1) * sizeof(int));
  float2* scoord = (float2*)alloc((size_t)BN * sizeof(float2));
  int* sorig = (int*)alloc((size_t)BN * sizeof(int));

  hipMemsetAsync(cnt, 0, (size_t)BN * sizeof(int), stream);
  grid_build_kernel<<<B, 1024, 0, stream>>>(coords, cell_start, scoord, sorig, N);
  knn_grid_kernel<<<(BN * 8 + 255) / 256, 256, 0, stream>>>(cell_start, scoord, sorig, knn_s, cnt, rev, N, BN);
  nbr_build_kernel<<<(BN + 255) / 256, 256, 0, stream>>>(knn_s, cnt, rev, nlist, nlcnt, BN);
  wconv_kernel<<<NLAYERS * 64, 256, 0, stream>>>(Wall, Wt);
  x2bf_perm_kernel<<<BN, 128, 0, stream>>>(nf, sorig, xs, N);

  for (int l = 0; l < NLAYERS; ++l) {
    agg_kernel<<<BN / 4, 256, 0, stream>>>(xs, nlist, nlcnt, aggb, N);
    gemm_mfma_kernel<<<512, 256, 0, stream>>>(
        aggb, Wt + (size_t)l * HIDDEN * HIDDEN, ball + (size_t)l * HIDDEN, tmpb);
    ln_relu_res_kernel<<<BN / 4, 256, 0, stream>>>(
        tmpb, gall + (size_t)l * HIDDEN, beall + (size_t)l * HIDDEN,
        xs, out, sorig, N, l > 0, l == NLAYERS - 1);
  }
}

// Round 9
// 254.999 us; speedup vs baseline: 1.0703x; 1.0703x over previous
//
#include <hip/hip_runtime.h>
#include <stdint.h>

#define HIDDEN 512
#define NLAYERS 3
#define KNN 8
#define CAP 64
#define NBMAX (KNN + CAP)   // combined fwd+rev neighbor list stride
#define EPSV 1e-5f
#define GRID 32
#define NCELL (GRID * GRID)

typedef unsigned long long u64;
typedef __attribute__((ext_vector_type(8))) short short8;   // 8 bf16 = 4 VGPRs
typedef __attribute__((ext_vector_type(4))) float f32x4;    // MFMA acc

// async global->LDS DMA, 16 B/lane; LDS dest = wave-uniform base + lane*16
#define GLL16(gp, lp)                                                         \
  __builtin_amdgcn_global_load_lds(                                           \
      (const __attribute__((address_space(1))) unsigned int*)(gp),            \
      (__attribute__((address_space(3))) unsigned int*)(lp), 16, 0, 0)

__device__ inline unsigned short f2bf(float x) {  // RNE fp32 -> bf16 bits
  union { float f; unsigned u; } v; v.f = x;
  unsigned r = v.u + 0x7FFFu + ((v.u >> 16) & 1u);
  return (unsigned short)(r >> 16);
}
__device__ inline float bf2f(unsigned short u) {
  return __uint_as_float((unsigned)u << 16);
}

// ---------------------------------------------------------------------------
// Grid build: one 1024-thread block per batch. Counting sort into 32x32 cells.
// Sorted order (scoord/sorig) is the processing order of the whole pipeline.
// ---------------------------------------------------------------------------
__global__ __launch_bounds__(1024) void grid_build_kernel(
    const float2* __restrict__ coords, int* __restrict__ cell_start,
    float2* __restrict__ scoord, int* __restrict__ sorig, int N) {
  __shared__ int hist[NCELL];
  __shared__ int offs[NCELL];
  int b = blockIdx.x;
  int t = threadIdx.x;
  hist[t] = 0;
  __syncthreads();
  const float2* cb = coords + (size_t)b * N;
  int mycell[4];
#pragma unroll
  for (int r = 0; r < 4; ++r) {
    int i = t + r * 1024;
    float2 c = cb[i];
    int cx = (int)(c.x * GRID); cx = cx < 0 ? 0 : (cx > GRID - 1 ? GRID - 1 : cx);
    int cy = (int)(c.y * GRID); cy = cy < 0 ? 0 : (cy > GRID - 1 ? GRID - 1 : cy);
    mycell[r] = cy * GRID + cx;
    atomicAdd(&hist[mycell[r]], 1);
  }
  __syncthreads();
  int v = hist[t];
  offs[t] = v;
  __syncthreads();
  for (int d = 1; d < NCELL; d <<= 1) {
    int add = (t >= d) ? offs[t - d] : 0;
    __syncthreads();
    offs[t] += add;
    __syncthreads();
  }
  int excl = offs[t] - v;
  cell_start[(size_t)b * (NCELL + 1) + t] = excl;
  if (t == 0) cell_start[(size_t)b * (NCELL + 1) + NCELL] = N;
  hist[t] = excl;
  __syncthreads();
#pragma unroll
  for (int r = 0; r < 4; ++r) {
    int i = t + r * 1024;
    int pos = atomicAdd(&hist[mycell[r]], 1);
    scoord[(size_t)b * N + pos] = cb[i];
    sorig[(size_t)b * N + pos] = i;
  }
}

// ---------------------------------------------------------------------------
// Gang-of-8 grid kNN (checker-bit-exact d2) with the reverse-adjacency build
// fused into the merge loop (owner lane atomics).
// ---------------------------------------------------------------------------
__global__ __launch_bounds__(256) void knn_grid_kernel(
    const int* __restrict__ cell_start, const float2* __restrict__ scoord,
    const int* __restrict__ sorig, int* __restrict__ knn_s,
    int* __restrict__ cnt, int* __restrict__ rev, int N, int BN) {
  int gang = (blockIdx.x * blockDim.x + threadIdx.x) >> 3;
  int sub = threadIdx.x & 7;
  if (gang >= BN) return;
  int b = gang / N;
  float2 cn = scoord[gang];
  float sqn = __fmaf_rn(cn.y, cn.y, __fmul_rn(cn.x, cn.x));
  int cx = (int)(cn.x * GRID); cx = cx < 0 ? 0 : (cx > GRID - 1 ? GRID - 1 : cx);
  int cy = (int)(cn.y * GRID); cy = cy < 0 ? 0 : (cy > GRID - 1 ? GRID - 1 : cy);
  const int* cs = cell_start + (size_t)b * (NCELL + 1);
  const float2* sc = scoord + (size_t)b * N;
  const int* so = sorig + (size_t)b * N;

  u64 list[KNN + 1];
#pragma unroll
  for (int j = 0; j <= KNN; ++j) list[j] = ~0ull;

  auto scan_cell = [&](int ux, int uy) {
    int c = uy * GRID + ux;
    int s = cs[c], e = cs[c + 1];
    for (int p = s + sub; p < e; p += 8) {
      float2 cm = sc[p];
      float sqm = __fmaf_rn(cm.y, cm.y, __fmul_rn(cm.x, cm.x));
      float dot = __fmaf_rn(cn.y, cm.y, __fmul_rn(cn.x, cm.x));
      float d2 = __fsub_rn(__fadd_rn(sqn, sqm), __fmul_rn(2.0f, dot));
      unsigned ub = __float_as_uint(d2);
      unsigned k32 = (ub & 0x80000000u) ? ~ub : (ub | 0x80000000u);
      u64 key = ((u64)k32 << 24) | ((u64)(unsigned)so[p] << 12) | (u64)(unsigned)p;
      if (key < list[KNN]) {
        u64 cur = key;
#pragma unroll
        for (int j = 0; j <= KNN; ++j) {
          u64 lo = list[j] < cur ? list[j] : cur;
          u64 hi = list[j] < cur ? cur : list[j];
          list[j] = lo;
          cur = hi;
        }
      }
    }
  };

  for (int q = 0; q <= GRID; ++q) {
    if (q == 0) {
      scan_cell(cx, cy);
    } else {
      int x0 = cx - q, x1 = cx + q, y0 = cy - q, y1 = cy + q;
      int xa = x0 < 0 ? 0 : x0, xb_ = x1 > GRID - 1 ? GRID - 1 : x1;
      for (int ux = xa; ux <= xb_; ++ux) {
        if (y0 >= 0) scan_cell(ux, y0);
        if (y1 <= GRID - 1) scan_cell(ux, y1);
      }
      int ya = (y0 + 1) < 0 ? 0 : y0 + 1, yb = (y1 - 1) > GRID - 1 ? GRID - 1 : y1 - 1;
      for (int uy = ya; uy <= yb; ++uy) {
        if (x0 >= 0) scan_cell(x0, uy);
        if (x1 <= GRID - 1) scan_cell(x1, uy);
      }
      float bound = (float)q * (1.0f / GRID);
      float thr = bound * bound - 1e-5f;
      int cntn = 0;
#pragma unroll
      for (int j = 0; j <= KNN; ++j) {
        unsigned k32 = (unsigned)(list[j] >> 24);
        float d2v = (k32 >= 0x80000000u) ? __uint_as_float(k32 & 0x7FFFFFFFu)
                                         : -__uint_as_float(~k32);
        cntn += (list[j] != ~0ull && d2v < thr) ? 1 : 0;
      }
#pragma unroll
      for (int o = 1; o < 8; o <<= 1) cntn += __shfl_xor(cntn, o, 64);
      if (cntn >= 9) break;
    }
  }

  int gl = gang - b * N;  // local sorted index of this node
  for (int r = 0; r <= KNN; ++r) {
    u64 cand = list[0];
    u64 mn = cand;
#pragma unroll
    for (int o = 1; o < 8; o <<= 1) {
      u64 v = __shfl_xor(mn, o, 64);
      mn = v < mn ? v : mn;
    }
    if (cand == mn) {
#pragma unroll
      for (int j = 0; j < KNN; ++j) list[j] = list[j + 1];
      list[KNN] = ~0ull;
      if (r > 0) {
        int m = (int)(mn & 0xFFFull);  // sorted-space neighbor
        knn_s[(size_t)gang * KNN + (r - 1)] = m;
        int gm = b * N + m;
        int pos = atomicAdd(&cnt[gm], 1);
        if (pos < CAP) rev[(size_t)gm * CAP + pos] = gl;
      }
    }
  }
}

// ---------------------------------------------------------------------------
// One-time combined neighbor list build: nlist[bn] = knn fwd (order kept) ++
// rev entries minus dups (order kept). Accumulation order in agg stays the
// old fwd-then-rev-dedup order (bit-identical), dedup runs once per session.
// ---------------------------------------------------------------------------
__global__ __launch_bounds__(256) void nbr_build_kernel(
    const int* __restrict__ knn, const int* __restrict__ cnt,
    const int* __restrict__ rev, int* __restrict__ nlist,
    int* __restrict__ nlcnt, int BN) {
  int bn = blockIdx.x * blockDim.x + threadIdx.x;
  if (bn >= BN) return;
  const int* my = knn + (size_t)bn * KNN;
  int* ol = nlist + (size_t)bn * NBMAX;
  int nb[KNN];
#pragma unroll
  for (int j = 0; j < KNN; ++j) { nb[j] = my[j]; ol[j] = nb[j]; }
  int m = KNN;
  int indeg = cnt[bn];
  if (indeg > CAP) indeg = CAP;
  const int* rv = rev + (size_t)bn * CAP;
  for (int i = 0; i < indeg; ++i) {
    int r = rv[i];
    bool dup = false;
#pragma unroll
    for (int j = 0; j < KNN; ++j) dup = dup || (r == nb[j]);
    if (!dup) ol[m++] = r;
  }
  nlcnt[bn] = m;
}

// ---------------------------------------------------------------------------
// Aggregation in sorted space: branch-free gather-sum over nlist.
// One WAVE per row (16 B/lane short8 loads), 256-thread blocks = 4 rows.
// XCD-aware block swizzle (T1): XCD k owns a contiguous 2048-row chunk
// (2 MB + halo -> L2-resident gather). Per-element accumulation order is
// unchanged (sequential over nlist) -> bit-identical output.
// ---------------------------------------------------------------------------
__global__ __launch_bounds__(256) void agg_kernel(const unsigned short* __restrict__ x,
                                                  const int* __restrict__ nlist,
                                                  const int* __restrict__ nlcnt,
                                                  unsigned short* __restrict__ aggb,
                                                  int N) {
  int bid = blockIdx.x;
  int nwg = gridDim.x;                       // BN/4, divisible by 8
  int blk = ((nwg & 7) == 0) ? ((bid & 7) * (nwg >> 3) + (bid >> 3)) : bid;
  int w = threadIdx.x >> 6, lane = threadIdx.x & 63;
  int bn = blk * 4 + w;                      // row this wave owns
  int b = bn / N;
  int m = nlcnt[bn];
  const int* nl = nlist + (size_t)bn * NBMAX;
  const unsigned short* xb = x + (size_t)b * N * HIDDEN + lane * 8;
  float acc[8] = {0.f, 0.f, 0.f, 0.f, 0.f, 0.f, 0.f, 0.f};
  int i = 0;
  for (; i + 4 <= m; i += 4) {
    int r0 = nl[i], r1 = nl[i + 1], r2 = nl[i + 2], r3 = nl[i + 3];
    short8 v0 = *(const short8*)(xb + (size_t)r0 * HIDDEN);
    short8 v1 = *(const short8*)(xb + (size_t)r1 * HIDDEN);
    short8 v2 = *(const short8*)(xb + (size_t)r2 * HIDDEN);
    short8 v3 = *(const short8*)(xb + (size_t)r3 * HIDDEN);
#pragma unroll
    for (int e = 0; e < 8; ++e) acc[e] += bf2f((unsigned short)v0[e]);
#pragma unroll
    for (int e = 0; e < 8; ++e) acc[e] += bf2f((unsigned short)v1[e]);
#pragma unroll
    for (int e = 0; e < 8; ++e) acc[e] += bf2f((unsigned short)v2[e]);
#pragma unroll
    for (int e = 0; e < 8; ++e) acc[e] += bf2f((unsigned short)v3[e]);
  }
  for (; i < m; ++i) {
    short8 v = *(const short8*)(xb + (size_t)nl[i] * HIDDEN);
#pragma unroll
    for (int e = 0; e < 8; ++e) acc[e] += bf2f((unsigned short)v[e]);
  }
  short8 o;
#pragma unroll
  for (int e = 0; e < 8; ++e) o[e] = (short)f2bf(acc[e]);
  *(short8*)(aggb + (size_t)bn * HIDDEN + lane * 8) = o;
}

// ---------------------------------------------------------------------------
// Initial features -> bf16, permuted to sorted order.
// ---------------------------------------------------------------------------
__global__ __launch_bounds__(128) void x2bf_perm_kernel(const float* __restrict__ x,
                                                        const int* __restrict__ sorig,
                                                        unsigned short* __restrict__ xs,
                                                        int N) {
  int row = blockIdx.x;
  int b = row / N;
  int src = b * N + sorig[row];
  int t = threadIdx.x;
  float4 v = ((const float4*)(x + (size_t)src * HIDDEN))[t];
  ushort4 o;
  o.x = f2bf(v.x); o.y = f2bf(v.y); o.z = f2bf(v.z); o.w = f2bf(v.w);
  ((ushort4*)(xs + (size_t)row * HIDDEN))[t] = o;
}

// ---------------------------------------------------------------------------
// W convert+transpose: W[l][k][n] fp32 -> Wt[l][n][k] bf16.
// ---------------------------------------------------------------------------
__global__ __launch_bounds__(256) void wconv_kernel(const float* __restrict__ W,
                                                    unsigned short* __restrict__ Wt) {
  __shared__ unsigned short tile[64][65];
  int l = blockIdx.x >> 6;
  int t6 = blockIdx.x & 63;
  int k0 = (t6 >> 3) * 64, n0 = (t6 & 7) * 64;
  const float* Wl = W + (size_t)l * HIDDEN * HIDDEN;
  unsigned short* Wtl = Wt + (size_t)l * HIDDEN * HIDDEN;
  int t = threadIdx.x;
#pragma unroll
  for (int r = 0; r < 4; ++r) {
    int row = (t >> 4) + r * 16;
    int col = (t & 15) * 4;
    float4 v = *(const float4*)(Wl + (size_t)(k0 + row) * HIDDEN + n0 + col);
    tile[col + 0][row] = f2bf(v.x);
    tile[col + 1][row] = f2bf(v.y);
    tile[col + 2][row] = f2bf(v.z);
    tile[col + 3][row] = f2bf(v.w);
  }
  __syncthreads();
#pragma unroll
  for (int r = 0; r < 4; ++r) {
    int row = (t >> 4) + r * 16;
    int col = (t & 15) * 4;
    ushort4 o;
    o.x = tile[row][col + 0]; o.y = tile[row][col + 1];
    o.z = tile[row][col + 2]; o.w = tile[row][col + 3];
    *(ushort4*)(Wtl + (size_t)(n0 + row) * HIDDEN + k0 + col) = o;
  }
}

// ---------------------------------------------------------------------------
// bf16 MFMA GEMM: tmpb = bf16(A @ W + bias). 128x128 tile, BK=32.
// Round-9: 8 waves (512 threads) instead of 4 — wave w owns a 64x32
// sub-tile (wr=w>>2 row half, wc=w&3 col quarter), acc[4][2]. Same tile,
// same staging traffic, same LDS (33 KB), but resident waves/SIMD double
// from 2 to 4 (grid 512 = 2 blocks/CU; 2 x 8 waves = 16/CU): the per-step
// vmcnt drain + barrier is hidden by 2x the TLP (m114 mechanism). Per-
// output-element MFMA sequence unchanged -> bit-identical.
// T3 2-phase double-buffer kept (round-7): prefetch next K-tile before
// computing current, one barrier per iter. Direct C store (round-8's LDS-
// staged epilogue regressed — reverted).
// 512-block grid with XCD swizzle (A row-panel L2-resident per XCD).
// ---------------------------------------------------------------------------
__global__ __launch_bounds__(512) void gemm_mfma_kernel(
    const unsigned short* __restrict__ A,
    const unsigned short* __restrict__ Wt,
    const float* __restrict__ bias,
    unsigned short* __restrict__ Cb) {
  __shared__ unsigned short As[2][128 * 32];
  __shared__ unsigned short Bs[2][128 * 32];
  int t = threadIdx.x;
  int bid = blockIdx.x;
  int sw = (bid & 7) * 64 + (bid >> 3);
  int m0 = (sw >> 2) * 128;
  int n0 = (sw & 3) * 128;
  int w = t >> 6, lane = t & 63;
  int wr = w >> 2, wc = w & 3;           // 2x4 wave grid, 64x32 sub-tiles
  int lm = lane & 15, q = lane >> 4;

  f32x4 acc[4][2];
#pragma unroll
  for (int i = 0; i < 4; ++i)
#pragma unroll
    for (int j = 0; j < 2; ++j) acc[i][j] = (f32x4){0.f, 0.f, 0.f, 0.f};

  int lrow = lane >> 2;        // 0..15 within a 16-row chunk
  int lcol = (lane & 3) * 8;   // 0,8,16,24
  // wave w stages As chunk w (rows w*16..+15) and Bs chunk w — same final
  // LDS content as the 4-wave version (chunk e = rows e*16, linear).
  const unsigned short* Arow = A + (size_t)(m0 + w * 16 + lrow) * HIDDEN + lcol;
  const unsigned short* Brow = Wt + (size_t)(n0 + w * 16 + lrow) * HIDDEN + lcol;

  // prologue: stage K-tile 0 into buffer 0
  GLL16(Arow, As[0] + w * 512);
  GLL16(Brow, Bs[0] + w * 512);
  __syncthreads();  // implicit vmcnt(0): tile 0 resident

  int cur = 0;
  for (int k0 = 0; k0 < HIDDEN; k0 += 32) {
    int nxt = cur ^ 1;
    if (k0 + 32 < HIDDEN) {   // prefetch next K-tile into the other buffer
      GLL16(Arow + k0 + 32, As[nxt] + w * 512);
      GLL16(Brow + k0 + 32, Bs[nxt] + w * 512);
    }
    short8 af[4], bfr[2];
#pragma unroll
    for (int i = 0; i < 4; ++i)
      af[i] = *(const short8*)(As[cur] + (wr * 64 + i * 16 + lm) * 32 + q * 8);
#pragma unroll
    for (int j = 0; j < 2; ++j)
      bfr[j] = *(const short8*)(Bs[cur] + (wc * 32 + j * 16 + lm) * 32 + q * 8);
#pragma unroll
    for (int i = 0; i < 4; ++i)
#pragma unroll
      for (int j = 0; j < 2; ++j)
        acc[i][j] = __builtin_amdgcn_mfma_f32_16x16x32_bf16(af[i], bfr[j], acc[i][j], 0, 0, 0);
    __syncthreads();  // vmcnt(0)+lgkmcnt(0): prefetch resident, reads done
    cur = nxt;
  }

#pragma unroll
  for (int i = 0; i < 4; ++i) {
    int row = m0 + wr * 64 + i * 16 + q * 4;
#pragma unroll
    for (int j = 0; j < 2; ++j) {
      int col = n0 + wc * 32 + j * 16 + lm;
      float bv = bias[col];
#pragma unroll
      for (int r = 0; r < 4; ++r)
        Cb[(size_t)(row + r) * HIDDEN + col] = f2bf(acc[i][j][r] + bv);
    }
  }
}

// ---------------------------------------------------------------------------
// LayerNorm + ReLU + residual, sorted space, bf16 tmp input. One wave per row;
// lane owns elements 8*lane..8*lane+7. Stats in fp32.
// XCD chunk swizzle: XCD k processes rows 2048k..2048k+2047 — the same rows
// gemm wrote (tmpb) and agg/prev-ln wrote (xs) on XCD k -> reads L2-local.
// final=0: xs[row] = bf16(result). final=1: out[perm(row)] = fp32 result.
// ---------------------------------------------------------------------------
__global__ __launch_bounds__(256) void ln_relu_res_kernel(
    const unsigned short* __restrict__ tb, const float* __restrict__ g,
    const float* __restrict__ be, unsigned short* __restrict__ xs,
    float* __restrict__ out, const int* __restrict__ sorig,
    int N, int addres, int final_) {
  int bid = blockIdx.x;
  int nwg = gridDim.x;                       // BN/4 = 4096, divisible by 8
  int blk = ((nwg & 7) == 0) ? ((bid & 7) * (nwg >> 3) + (bid >> 3)) : bid;
  int row = (blk << 2) + (threadIdx.x >> 6);
  int lane = threadIdx.x & 63;
  uint4 u = ((const uint4*)(tb + (size_t)row * HIDDEN))[lane];
  float v[8];
  v[0] = bf2f((unsigned short)(u.x & 0xFFFFu)); v[1] = bf2f((unsigned short)(u.x >> 16));
  v[2] = bf2f((unsigned short)(u.y & 0xFFFFu)); v[3] = bf2f((unsigned short)(u.y >> 16));
  v[4] = bf2f((unsigned short)(u.z & 0xFFFFu)); v[5] = bf2f((unsigned short)(u.z >> 16));
  v[6] = bf2f((unsigned short)(u.w & 0xFFFFu)); v[7] = bf2f((unsigned short)(u.w >> 16));
  float s = 0.f, ss = 0.f;
#pragma unroll
  for (int k = 0; k < 8; ++k) { s += v[k]; ss += v[k] * v[k]; }
#pragma unroll
  for (int o = 32; o > 0; o >>= 1) {
    s += __shfl_xor(s, o, 64);
    ss += __shfl_xor(ss, o, 64);
  }
  float mu = s * (1.0f / HIDDEN);
  float var = ss * (1.0f / HIDDEN) - mu * mu;
  float inv = rsqrtf(var + EPSV);
  float4 g0 = ((const float4*)g)[2 * lane], g1 = ((const float4*)g)[2 * lane + 1];
  float4 b0 = ((const float4*)be)[2 * lane], b1 = ((const float4*)be)[2 * lane + 1];
  float gv[8] = {g0.x, g0.y, g0.z, g0.w, g1.x, g1.y, g1.z, g1.w};
  float bv[8] = {b0.x, b0.y, b0.z, b0.w, b1.x, b1.y, b1.z, b1.w};
  float o8[8];
#pragma unroll
  for (int k = 0; k < 8; ++k)
    o8[k] = fmaxf((v[k] - mu) * inv * gv[k] + bv[k], 0.f);
  ushort4* xrow = (ushort4*)(xs + (size_t)row * HIDDEN);
  if (addres) {
    ushort4 r0 = xrow[2 * lane], r1 = xrow[2 * lane + 1];
    o8[0] += bf2f(r0.x); o8[1] += bf2f(r0.y); o8[2] += bf2f(r0.z); o8[3] += bf2f(r0.w);
    o8[4] += bf2f(r1.x); o8[5] += bf2f(r1.y); o8[6] += bf2f(r1.z); o8[7] += bf2f(r1.w);
  }
  if (final_) {
    int b = row / N;
    size_t dst = (size_t)(b * N + sorig[row]) * HIDDEN;
    float4 w0 = {o8[0], o8[1], o8[2], o8[3]};
    float4 w1 = {o8[4], o8[5], o8[6], o8[7]};
    ((float4*)(out + dst))[2 * lane] = w0;
    ((float4*)(out + dst))[2 * lane + 1] = w1;
  } else {
    ushort4 q0, q1;
    q0.x = f2bf(o8[0]); q0.y = f2bf(o8[1]); q0.z = f2bf(o8[2]); q0.w = f2bf(o8[3]);
    q1.x = f2bf(o8[4]); q1.y = f2bf(o8[5]); q1.z = f2bf(o8[6]); q1.w = f2bf(o8[7]);
    xrow[2 * lane] = q0;
    xrow[2 * lane + 1] = q1;
  }
}

// ---------------------------------------------------------------------------
extern "C" void kernel_launch(void* const* d_in, const int* in_sizes, int n_in,
                              void* d_out, int out_size, void* d_ws, size_t ws_size,
                              hipStream_t stream) {
  const float* nf = (const float*)d_in[0];
  const float2* coords = (const float2*)d_in[1];
  const float* Wall = (const float*)d_in[2];
  const float* ball = (const float*)d_in[3];
  const float* gall = (const float*)d_in[4];
  const float* beall = (const float*)d_in[5];
  float* out = (float*)d_out;

  int BN = in_sizes[0] / HIDDEN;  // 16384
  int N = 4096;
  int B = BN / N;

  char* ws = (char*)d_ws;
  size_t off = 0;
  auto alloc = [&](size_t bytes) -> void* {
    off = (off + 255) & ~(size_t)255;
    void* p = ws + off;
    off += bytes;
    return p;
  };
  int* knn_s = (int*)alloc((size_t)BN * KNN * sizeof(int));
  int* cnt = (int*)alloc((size_t)BN * sizeof(int));
  int* rev = (int*)alloc((size_t)BN * CAP * sizeof(int));
  int* nlist = (int*)alloc((size_t)BN * NBMAX * sizeof(int));
  int* nlcnt = (int*)alloc((size_t)BN * sizeof(int));
  unsigned short* aggb = (unsigned short*)alloc((size_t)BN * HIDDEN * sizeof(unsigned short));
  unsigned short* tmpb = (unsigned short*)alloc((size_t)BN * HIDDEN * sizeof(unsigned short));
  unsigned short* Wt = (unsigned short*)alloc((size_t)NLAYERS * HIDDEN * HIDDEN * sizeof(unsigned short));
  unsigned short* xs = (unsigned short*)alloc((size_t)BN * HIDDEN * sizeof(unsigned short));
  int* cell_start = (int*)alloc((size_t)B * (NCELL + 1) * sizeof(int));
  float2* scoord = (float2*)alloc((size_t)BN * sizeof(float2));
  int* sorig = (int*)alloc((size_t)BN * sizeof(int));

  hipMemsetAsync(cnt, 0, (size_t)BN * sizeof(int), stream);
  grid_build_kernel<<<B, 1024, 0, stream>>>(coords, cell_start, scoord, sorig, N);
  knn_grid_kernel<<<(BN * 8 + 255) / 256, 256, 0, stream>>>(cell_start, scoord, sorig, knn_s, cnt, rev, N, BN);
  nbr_build_kernel<<<(BN + 255) / 256, 256, 0, stream>>>(knn_s, cnt, rev, nlist, nlcnt, BN);
  wconv_kernel<<<NLAYERS * 64, 256, 0, stream>>>(Wall, Wt);
  x2bf_perm_kernel<<<BN, 128, 0, stream>>>(nf, sorig, xs, N);

  for (int l = 0; l < NLAYERS; ++l) {
    agg_kernel<<<BN / 4, 256, 0, stream>>>(xs, nlist, nlcnt, aggb, N);
    gemm_mfma_kernel<<<512, 512, 0, stream>>>(
        aggb, Wt + (size_t)l * HIDDEN * HIDDEN, ball + (size_t)l * HIDDEN, tmpb);
    ln_relu_res_kernel<<<BN / 4, 256, 0, stream>>>(
        tmpb, gall + (size_t)l * HIDDEN, beall + (size_t)l * HIDDEN,
        xs, out, sorig, N, l > 0, l == NLAYERS - 1);
  }
}

// Round 10
// 250.225 us; speedup vs baseline: 1.0907x; 1.0191x over previous
//
#include <hip/hip_runtime.h>
#include <stdint.h>

#define HIDDEN 512
#define NLAYERS 3
#define KNN 8
#define CAP 64
#define NBMAX (KNN + CAP)   // combined fwd+rev neighbor list stride
#define EPSV 1e-5f
#define GRID 32
#define NCELL (GRID * GRID)

typedef unsigned long long u64;
typedef __attribute__((ext_vector_type(8))) short short8;   // 8 bf16 = 4 VGPRs
typedef __attribute__((ext_vector_type(4))) float f32x4;    // MFMA acc

// async global->LDS DMA, 16 B/lane; LDS dest = wave-uniform base + lane*16
#define GLL16(gp, lp)                                                         \
  __builtin_amdgcn_global_load_lds(                                           \
      (const __attribute__((address_space(1))) unsigned int*)(gp),            \
      (__attribute__((address_space(3))) unsigned int*)(lp), 16, 0, 0)

__device__ inline unsigned short f2bf(float x) {  // RNE fp32 -> bf16 bits
  union { float f; unsigned u; } v; v.f = x;
  unsigned r = v.u + 0x7FFFu + ((v.u >> 16) & 1u);
  return (unsigned short)(r >> 16);
}
__device__ inline float bf2f(unsigned short u) {
  return __uint_as_float((unsigned)u << 16);
}

// ---------------------------------------------------------------------------
// Grid build: one 1024-thread block per batch. Counting sort into 32x32 cells.
// Sorted order (scoord/sorig) is the processing order of the whole pipeline.
// Round-10: also zeroes cnt[] (replaces the hipMemsetAsync dispatch; runs
// before knn in stream order).
// ---------------------------------------------------------------------------
__global__ __launch_bounds__(1024) void grid_build_kernel(
    const float2* __restrict__ coords, int* __restrict__ cell_start,
    float2* __restrict__ scoord, int* __restrict__ sorig,
    int* __restrict__ cnt, int N) {
  __shared__ int hist[NCELL];
  __shared__ int offs[NCELL];
  int b = blockIdx.x;
  int t = threadIdx.x;
  hist[t] = 0;
#pragma unroll
  for (int r = 0; r < 4; ++r) cnt[(size_t)b * N + t + r * 1024] = 0;
  __syncthreads();
  const float2* cb = coords + (size_t)b * N;
  int mycell[4];
#pragma unroll
  for (int r = 0; r < 4; ++r) {
    int i = t + r * 1024;
    float2 c = cb[i];
    int cx = (int)(c.x * GRID); cx = cx < 0 ? 0 : (cx > GRID - 1 ? GRID - 1 : cx);
    int cy = (int)(c.y * GRID); cy = cy < 0 ? 0 : (cy > GRID - 1 ? GRID - 1 : cy);
    mycell[r] = cy * GRID + cx;
    atomicAdd(&hist[mycell[r]], 1);
  }
  __syncthreads();
  int v = hist[t];
  offs[t] = v;
  __syncthreads();
  for (int d = 1; d < NCELL; d <<= 1) {
    int add = (t >= d) ? offs[t - d] : 0;
    __syncthreads();
    offs[t] += add;
    __syncthreads();
  }
  int excl = offs[t] - v;
  cell_start[(size_t)b * (NCELL + 1) + t] = excl;
  if (t == 0) cell_start[(size_t)b * (NCELL + 1) + NCELL] = N;
  hist[t] = excl;
  __syncthreads();
#pragma unroll
  for (int r = 0; r < 4; ++r) {
    int i = t + r * 1024;
    int pos = atomicAdd(&hist[mycell[r]], 1);
    scoord[(size_t)b * N + pos] = cb[i];
    sorig[(size_t)b * N + pos] = i;
  }
}

// ---------------------------------------------------------------------------
// Gang-of-8 grid kNN (checker-bit-exact d2) with the reverse-adjacency build
// fused into the merge loop (owner lane atomics).
// ---------------------------------------------------------------------------
__global__ __launch_bounds__(256) void knn_grid_kernel(
    const int* __restrict__ cell_start, const float2* __restrict__ scoord,
    const int* __restrict__ sorig, int* __restrict__ knn_s,
    int* __restrict__ cnt, int* __restrict__ rev, int N, int BN) {
  int gang = (blockIdx.x * blockDim.x + threadIdx.x) >> 3;
  int sub = threadIdx.x & 7;
  if (gang >= BN) return;
  int b = gang / N;
  float2 cn = scoord[gang];
  float sqn = __fmaf_rn(cn.y, cn.y, __fmul_rn(cn.x, cn.x));
  int cx = (int)(cn.x * GRID); cx = cx < 0 ? 0 : (cx > GRID - 1 ? GRID - 1 : cx);
  int cy = (int)(cn.y * GRID); cy = cy < 0 ? 0 : (cy > GRID - 1 ? GRID - 1 : cy);
  const int* cs = cell_start + (size_t)b * (NCELL + 1);
  const float2* sc = scoord + (size_t)b * N;
  const int* so = sorig + (size_t)b * N;

  u64 list[KNN + 1];
#pragma unroll
  for (int j = 0; j <= KNN; ++j) list[j] = ~0ull;

  auto scan_cell = [&](int ux, int uy) {
    int c = uy * GRID + ux;
    int s = cs[c], e = cs[c + 1];
    for (int p = s + sub; p < e; p += 8) {
      float2 cm = sc[p];
      float sqm = __fmaf_rn(cm.y, cm.y, __fmul_rn(cm.x, cm.x));
      float dot = __fmaf_rn(cn.y, cm.y, __fmul_rn(cn.x, cm.x));
      float d2 = __fsub_rn(__fadd_rn(sqn, sqm), __fmul_rn(2.0f, dot));
      unsigned ub = __float_as_uint(d2);
      unsigned k32 = (ub & 0x80000000u) ? ~ub : (ub | 0x80000000u);
      u64 key = ((u64)k32 << 24) | ((u64)(unsigned)so[p] << 12) | (u64)(unsigned)p;
      if (key < list[KNN]) {
        u64 cur = key;
#pragma unroll
        for (int j = 0; j <= KNN; ++j) {
          u64 lo = list[j] < cur ? list[j] : cur;
          u64 hi = list[j] < cur ? cur : list[j];
          list[j] = lo;
          cur = hi;
        }
      }
    }
  };

  for (int q = 0; q <= GRID; ++q) {
    if (q == 0) {
      scan_cell(cx, cy);
    } else {
      int x0 = cx - q, x1 = cx + q, y0 = cy - q, y1 = cy + q;
      int xa = x0 < 0 ? 0 : x0, xb_ = x1 > GRID - 1 ? GRID - 1 : x1;
      for (int ux = xa; ux <= xb_; ++ux) {
        if (y0 >= 0) scan_cell(ux, y0);
        if (y1 <= GRID - 1) scan_cell(ux, y1);
      }
      int ya = (y0 + 1) < 0 ? 0 : y0 + 1, yb = (y1 - 1) > GRID - 1 ? GRID - 1 : y1 - 1;
      for (int uy = ya; uy <= yb; ++uy) {
        if (x0 >= 0) scan_cell(x0, uy);
        if (x1 <= GRID - 1) scan_cell(x1, uy);
      }
      float bound = (float)q * (1.0f / GRID);
      float thr = bound * bound - 1e-5f;
      int cntn = 0;
#pragma unroll
      for (int j = 0; j <= KNN; ++j) {
        unsigned k32 = (unsigned)(list[j] >> 24);
        float d2v = (k32 >= 0x80000000u) ? __uint_as_float(k32 & 0x7FFFFFFFu)
                                         : -__uint_as_float(~k32);
        cntn += (list[j] != ~0ull && d2v < thr) ? 1 : 0;
      }
#pragma unroll
      for (int o = 1; o < 8; o <<= 1) cntn += __shfl_xor(cntn, o, 64);
      if (cntn >= 9) break;
    }
  }

  int gl = gang - b * N;  // local sorted index of this node
  for (int r = 0; r <= KNN; ++r) {
    u64 cand = list[0];
    u64 mn = cand;
#pragma unroll
    for (int o = 1; o < 8; o <<= 1) {
      u64 v = __shfl_xor(mn, o, 64);
      mn = v < mn ? v : mn;
    }
    if (cand == mn) {
#pragma unroll
      for (int j = 0; j < KNN; ++j) list[j] = list[j + 1];
      list[KNN] = ~0ull;
      if (r > 0) {
        int m = (int)(mn & 0xFFFull);  // sorted-space neighbor
        knn_s[(size_t)gang * KNN + (r - 1)] = m;
        int gm = b * N + m;
        int pos = atomicAdd(&cnt[gm], 1);
        if (pos < CAP) rev[(size_t)gm * CAP + pos] = gl;
      }
    }
  }
}

// ---------------------------------------------------------------------------
// One-time combined neighbor list build: nlist[bn] = knn fwd (order kept) ++
// rev entries minus dups (order kept). Accumulation order in agg stays the
// old fwd-then-rev-dedup order (bit-identical), dedup runs once per session.
// ---------------------------------------------------------------------------
__global__ __launch_bounds__(256) void nbr_build_kernel(
    const int* __restrict__ knn, const int* __restrict__ cnt,
    const int* __restrict__ rev, int* __restrict__ nlist,
    int* __restrict__ nlcnt, int BN) {
  int bn = blockIdx.x * blockDim.x + threadIdx.x;
  if (bn >= BN) return;
  const int* my = knn + (size_t)bn * KNN;
  int* ol = nlist + (size_t)bn * NBMAX;
  int nb[KNN];
#pragma unroll
  for (int j = 0; j < KNN; ++j) { nb[j] = my[j]; ol[j] = nb[j]; }
  int m = KNN;
  int indeg = cnt[bn];
  if (indeg > CAP) indeg = CAP;
  const int* rv = rev + (size_t)bn * CAP;
  for (int i = 0; i < indeg; ++i) {
    int r = rv[i];
    bool dup = false;
#pragma unroll
    for (int j = 0; j < KNN; ++j) dup = dup || (r == nb[j]);
    if (!dup) ol[m++] = r;
  }
  nlcnt[bn] = m;
}

// ---------------------------------------------------------------------------
// Merged prep kernel (block-range dispatch): blocks 0..191 = W convert+
// transpose (W[l][k][n] fp32 -> Wt[l][n][k] bf16); blocks 192.. = initial
// features -> bf16 permuted to sorted order (2 rows per 256-thread block).
// Saves a launch boundary and backfills wconv's 192-block underfill.
// ---------------------------------------------------------------------------
__global__ __launch_bounds__(256) void prep_kernel(
    const float* __restrict__ W, unsigned short* __restrict__ Wt,
    const float* __restrict__ x, const int* __restrict__ sorig,
    unsigned short* __restrict__ xs, int N) {
  __shared__ unsigned short tile[64][65];
  int blk = blockIdx.x;
  int t = threadIdx.x;
  if (blk < 192) {  // ---- wconv part
    int l = blk >> 6;
    int t6 = blk & 63;
    int k0 = (t6 >> 3) * 64, n0 = (t6 & 7) * 64;
    const float* Wl = W + (size_t)l * HIDDEN * HIDDEN;
    unsigned short* Wtl = Wt + (size_t)l * HIDDEN * HIDDEN;
#pragma unroll
    for (int r = 0; r < 4; ++r) {
      int row = (t >> 4) + r * 16;
      int col = (t & 15) * 4;
      float4 v = *(const float4*)(Wl + (size_t)(k0 + row) * HIDDEN + n0 + col);
      tile[col + 0][row] = f2bf(v.x);
      tile[col + 1][row] = f2bf(v.y);
      tile[col + 2][row] = f2bf(v.z);
      tile[col + 3][row] = f2bf(v.w);
    }
    __syncthreads();
#pragma unroll
    for (int r = 0; r < 4; ++r) {
      int row = (t >> 4) + r * 16;
      int col = (t & 15) * 4;
      ushort4 o;
      o.x = tile[row][col + 0]; o.y = tile[row][col + 1];
      o.z = tile[row][col + 2]; o.w = tile[row][col + 3];
      *(ushort4*)(Wtl + (size_t)(n0 + row) * HIDDEN + k0 + col) = o;
    }
  } else {          // ---- x2bf_perm part: 2 rows per block
    int row = (blk - 192) * 2 + (t >> 7);
    int tt = t & 127;
    int b = row / N;
    int src = b * N + sorig[row];
    float4 v = ((const float4*)(x + (size_t)src * HIDDEN))[tt];
    ushort4 o;
    o.x = f2bf(v.x); o.y = f2bf(v.y); o.z = f2bf(v.z); o.w = f2bf(v.w);
    ((ushort4*)(xs + (size_t)row * HIDDEN))[tt] = o;
  }
}

// ---------------------------------------------------------------------------
// Aggregation in sorted space: branch-free gather-sum over nlist.
// One WAVE per row (16 B/lane short8 loads), 256-thread blocks = 4 rows.
// XCD-aware block swizzle (T1): XCD k owns a contiguous 2048-row chunk
// (2 MB + halo -> L2-resident gather). Per-element accumulation order is
// unchanged (sequential over nlist) -> bit-identical output.
// ---------------------------------------------------------------------------
__global__ __launch_bounds__(256) void agg_kernel(const unsigned short* __restrict__ x,
                                                  const int* __restrict__ nlist,
                                                  const int* __restrict__ nlcnt,
                                                  unsigned short* __restrict__ aggb,
                                                  int N) {
  int bid = blockIdx.x;
  int nwg = gridDim.x;                       // BN/4, divisible by 8
  int blk = ((nwg & 7) == 0) ? ((bid & 7) * (nwg >> 3) + (bid >> 3)) : bid;
  int w = threadIdx.x >> 6, lane = threadIdx.x & 63;
  int bn = blk * 4 + w;                      // row this wave owns
  int b = bn / N;
  int m = nlcnt[bn];
  const int* nl = nlist + (size_t)bn * NBMAX;
  const unsigned short* xb = x + (size_t)b * N * HIDDEN + lane * 8;
  float acc[8] = {0.f, 0.f, 0.f, 0.f, 0.f, 0.f, 0.f, 0.f};
  int i = 0;
  for (; i + 4 <= m; i += 4) {
    int r0 = nl[i], r1 = nl[i + 1], r2 = nl[i + 2], r3 = nl[i + 3];
    short8 v0 = *(const short8*)(xb + (size_t)r0 * HIDDEN);
    short8 v1 = *(const short8*)(xb + (size_t)r1 * HIDDEN);
    short8 v2 = *(const short8*)(xb + (size_t)r2 * HIDDEN);
    short8 v3 = *(const short8*)(xb + (size_t)r3 * HIDDEN);
#pragma unroll
    for (int e = 0; e < 8; ++e) acc[e] += bf2f((unsigned short)v0[e]);
#pragma unroll
    for (int e = 0; e < 8; ++e) acc[e] += bf2f((unsigned short)v1[e]);
#pragma unroll
    for (int e = 0; e < 8; ++e) acc[e] += bf2f((unsigned short)v2[e]);
#pragma unroll
    for (int e = 0; e < 8; ++e) acc[e] += bf2f((unsigned short)v3[e]);
  }
  for (; i < m; ++i) {
    short8 v = *(const short8*)(xb + (size_t)nl[i] * HIDDEN);
#pragma unroll
    for (int e = 0; e < 8; ++e) acc[e] += bf2f((unsigned short)v[e]);
  }
  short8 o;
#pragma unroll
  for (int e = 0; e < 8; ++e) o[e] = (short)f2bf(acc[e]);
  *(short8*)(aggb + (size_t)bn * HIDDEN + lane * 8) = o;
}

// ---------------------------------------------------------------------------
// bf16 MFMA GEMM: tmpb = bf16(A @ W + bias). 128x128 tile, BK=32, 4 waves 2x2.
// T3-minimum 2-phase double-buffer (round-7 best): prefetch next K-tile's
// global_load_lds BEFORE computing the current tile, one barrier per iter.
// Direct C store (round-8 LDS-staged epilogue regressed; round-9 8-wave
// split regressed — this is the proven config).
// 512-block grid with XCD swizzle (A row-panel L2-resident per XCD).
// ---------------------------------------------------------------------------
__global__ __launch_bounds__(256) void gemm_mfma_kernel(
    const unsigned short* __restrict__ A,
    const unsigned short* __restrict__ Wt,
    const float* __restrict__ bias,
    unsigned short* __restrict__ Cb) {
  __shared__ unsigned short As[2][128 * 32];
  __shared__ unsigned short Bs[2][128 * 32];
  int t = threadIdx.x;
  int bid = blockIdx.x;
  int sw = (bid & 7) * 64 + (bid >> 3);
  int m0 = (sw >> 2) * 128;
  int n0 = (sw & 3) * 128;
  int w = t >> 6, lane = t & 63;
  int wr = w >> 1, wc = w & 1;
  int lm = lane & 15, q = lane >> 4;

  f32x4 acc[4][4];
#pragma unroll
  for (int i = 0; i < 4; ++i)
#pragma unroll
    for (int j = 0; j < 4; ++j) acc[i][j] = (f32x4){0.f, 0.f, 0.f, 0.f};

  int lrow = lane >> 2;        // 0..15 within a 16-row chunk
  int lcol = (lane & 3) * 8;   // 0,8,16,24
  int e0 = w, e1 = w + 4;      // chunk ids this wave stages

  const unsigned short* Arow0 = A + (size_t)(m0 + e0 * 16 + lrow) * HIDDEN + lcol;
  const unsigned short* Arow1 = A + (size_t)(m0 + e1 * 16 + lrow) * HIDDEN + lcol;
  const unsigned short* Brow0 = Wt + (size_t)(n0 + e0 * 16 + lrow) * HIDDEN + lcol;
  const unsigned short* Brow1 = Wt + (size_t)(n0 + e1 * 16 + lrow) * HIDDEN + lcol;

  // prologue: stage K-tile 0 into buffer 0
  GLL16(Arow0, As[0] + e0 * 512);
  GLL16(Arow1, As[0] + e1 * 512);
  GLL16(Brow0, Bs[0] + e0 * 512);
  GLL16(Brow1, Bs[0] + e1 * 512);
  __syncthreads();  // implicit vmcnt(0): tile 0 resident

  int cur = 0;
  for (int k0 = 0; k0 < HIDDEN; k0 += 32) {
    int nxt = cur ^ 1;
    if (k0 + 32 < HIDDEN) {   // prefetch next K-tile into the other buffer
      GLL16(Arow0 + k0 + 32, As[nxt] + e0 * 512);
      GLL16(Arow1 + k0 + 32, As[nxt] + e1 * 512);
      GLL16(Brow0 + k0 + 32, Bs[nxt] + e0 * 512);
      GLL16(Brow1 + k0 + 32, Bs[nxt] + e1 * 512);
    }
    short8 af[4], bfr[4];
#pragma unroll
    for (int i = 0; i < 4; ++i)
      af[i] = *(const short8*)(As[cur] + (wr * 64 + i * 16 + lm) * 32 + q * 8);
#pragma unroll
    for (int j = 0; j < 4; ++j)
      bfr[j] = *(const short8*)(Bs[cur] + (wc * 64 + j * 16 + lm) * 32 + q * 8);
#pragma unroll
    for (int i = 0; i < 4; ++i)
#pragma unroll
      for (int j = 0; j < 4; ++j)
        acc[i][j] = __builtin_amdgcn_mfma_f32_16x16x32_bf16(af[i], bfr[j], acc[i][j], 0, 0, 0);
    __syncthreads();  // vmcnt(0)+lgkmcnt(0): prefetch resident, reads done
    cur = nxt;
  }

#pragma unroll
  for (int i = 0; i < 4; ++i) {
    int row = m0 + wr * 64 + i * 16 + q * 4;
#pragma unroll
    for (int j = 0; j < 4; ++j) {
      int col = n0 + wc * 64 + j * 16 + lm;
      float bv = bias[col];
#pragma unroll
      for (int r = 0; r < 4; ++r)
        Cb[(size_t)(row + r) * HIDDEN + col] = f2bf(acc[i][j][r] + bv);
    }
  }
}

// ---------------------------------------------------------------------------
// LayerNorm + ReLU + residual, sorted space, bf16 tmp input. One wave per row;
// lane owns elements 8*lane..8*lane+7. Stats in fp32.
// XCD chunk swizzle: XCD k processes rows 2048k..2048k+2047 — the same rows
// gemm wrote (tmpb) and agg/prev-ln wrote (xs) on XCD k -> reads L2-local.
// final=0: xs[row] = bf16(result). final=1: out[perm(row)] = fp32 result.
// ---------------------------------------------------------------------------
__global__ __launch_bounds__(256) void ln_relu_res_kernel(
    const unsigned short* __restrict__ tb, const float* __restrict__ g,
    const float* __restrict__ be, unsigned short* __restrict__ xs,
    float* __restrict__ out, const int* __restrict__ sorig,
    int N, int addres, int final_) {
  int bid = blockIdx.x;
  int nwg = gridDim.x;                       // BN/4 = 4096, divisible by 8
  int blk = ((nwg & 7) == 0) ? ((bid & 7) * (nwg >> 3) + (bid >> 3)) : bid;
  int row = (blk << 2) + (threadIdx.x >> 6);
  int lane = threadIdx.x & 63;
  uint4 u = ((const uint4*)(tb + (size_t)row * HIDDEN))[lane];
  float v[8];
  v[0] = bf2f((unsigned short)(u.x & 0xFFFFu)); v[1] = bf2f((unsigned short)(u.x >> 16));
  v[2] = bf2f((unsigned short)(u.y & 0xFFFFu)); v[3] = bf2f((unsigned short)(u.y >> 16));
  v[4] = bf2f((unsigned short)(u.z & 0xFFFFu)); v[5] = bf2f((unsigned short)(u.z >> 16));
  v[6] = bf2f((unsigned short)(u.w & 0xFFFFu)); v[7] = bf2f((unsigned short)(u.w >> 16));
  float s = 0.f, ss = 0.f;
#pragma unroll
  for (int k = 0; k < 8; ++k) { s += v[k]; ss += v[k] * v[k]; }
#pragma unroll
  for (int o = 32; o > 0; o >>= 1) {
    s += __shfl_xor(s, o, 64);
    ss += __shfl_xor(ss, o, 64);
  }
  float mu = s * (1.0f / HIDDEN);
  float var = ss * (1.0f / HIDDEN) - mu * mu;
  float inv = rsqrtf(var + EPSV);
  float4 g0 = ((const float4*)g)[2 * lane], g1 = ((const float4*)g)[2 * lane + 1];
  float4 b0 = ((const float4*)be)[2 * lane], b1 = ((const float4*)be)[2 * lane + 1];
  float gv[8] = {g0.x, g0.y, g0.z, g0.w, g1.x, g1.y, g1.z, g1.w};
  float bv[8] = {b0.x, b0.y, b0.z, b0.w, b1.x, b1.y, b1.z, b1.w};
  float o8[8];
#pragma unroll
  for (int k = 0; k < 8; ++k)
    o8[k] = fmaxf((v[k] - mu) * inv * gv[k] + bv[k], 0.f);
  ushort4* xrow = (ushort4*)(xs + (size_t)row * HIDDEN);
  if (addres) {
    ushort4 r0 = xrow[2 * lane], r1 = xrow[2 * lane + 1];
    o8[0] += bf2f(r0.x); o8[1] += bf2f(r0.y); o8[2] += bf2f(r0.z); o8[3] += bf2f(r0.w);
    o8[4] += bf2f(r1.x); o8[5] += bf2f(r1.y); o8[6] += bf2f(r1.z); o8[7] += bf2f(r1.w);
  }
  if (final_) {
    int b = row / N;
    size_t dst = (size_t)(b * N + sorig[row]) * HIDDEN;
    float4 w0 = {o8[0], o8[1], o8[2], o8[3]};
    float4 w1 = {o8[4], o8[5], o8[6], o8[7]};
    ((float4*)(out + dst))[2 * lane] = w0;
    ((float4*)(out + dst))[2 * lane + 1] = w1;
  } else {
    ushort4 q0, q1;
    q0.x = f2bf(o8[0]); q0.y = f2bf(o8[1]); q0.z = f2bf(o8[2]); q0.w = f2bf(o8[3]);
    q1.x = f2bf(o8[4]); q1.y = f2bf(o8[5]); q1.z = f2bf(o8[6]); q1.w = f2bf(o8[7]);
    xrow[2 * lane] = q0;
    xrow[2 * lane + 1] = q1;
  }
}

// ---------------------------------------------------------------------------
extern "C" void kernel_launch(void* const* d_in, const int* in_sizes, int n_in,
                              void* d_out, int out_size, void* d_ws, size_t ws_size,
                              hipStream_t stream) {
  const float* nf = (const float*)d_in[0];
  const float2* coords = (const float2*)d_in[1];
  const float* Wall = (const float*)d_in[2];
  const float* ball = (const float*)d_in[3];
  const float* gall = (const float*)d_in[4];
  const float* beall = (const float*)d_in[5];
  float* out = (float*)d_out;

  int BN = in_sizes[0] / HIDDEN;  // 16384
  int N = 4096;
  int B = BN / N;

  char* ws = (char*)d_ws;
  size_t off = 0;
  auto alloc = [&](size_t bytes) -> void* {
    off = (off + 255) & ~(size_t)255;
    void* p = ws + off;
    off += bytes;
    return p;
  };
  int* knn_s = (int*)alloc((size_t)BN * KNN * sizeof(int));
  int* cnt = (int*)alloc((size_t)BN * sizeof(int));
  int* rev = (int*)alloc((size_t)BN * CAP * sizeof(int));
  int* nlist = (int*)alloc((size_t)BN * NBMAX * sizeof(int));
  int* nlcnt = (int*)alloc((size_t)BN * sizeof(int));
  unsigned short* aggb = (unsigned short*)alloc((size_t)BN * HIDDEN * sizeof(unsigned short));
  unsigned short* tmpb = (unsigned short*)alloc((size_t)BN * HIDDEN * sizeof(unsigned short));
  unsigned short* Wt = (unsigned short*)alloc((size_t)NLAYERS * HIDDEN * HIDDEN * sizeof(unsigned short));
  unsigned short* xs = (unsigned short*)alloc((size_t)BN * HIDDEN * sizeof(unsigned short));
  int* cell_start = (int*)alloc((size_t)B * (NCELL + 1) * sizeof(int));
  float2* scoord = (float2*)alloc((size_t)BN * sizeof(float2));
  int* sorig = (int*)alloc((size_t)BN * sizeof(int));

  grid_build_kernel<<<B, 1024, 0, stream>>>(coords, cell_start, scoord, sorig, cnt, N);
  knn_grid_kernel<<<(BN * 8 + 255) / 256, 256, 0, stream>>>(cell_start, scoord, sorig, knn_s, cnt, rev, N, BN);
  nbr_build_kernel<<<(BN + 255) / 256, 256, 0, stream>>>(knn_s, cnt, rev, nlist, nlcnt, BN);
  prep_kernel<<<192 + BN / 2, 256, 0, stream>>>(Wall, Wt, nf, sorig, xs, N);

  for (int l = 0; l < NLAYERS; ++l) {
    agg_kernel<<<BN / 4, 256, 0, stream>>>(xs, nlist, nlcnt, aggb, N);
    gemm_mfma_kernel<<<512, 256, 0, stream>>>(
        aggb, Wt + (size_t)l * HIDDEN * HIDDEN, ball + (size_t)l * HIDDEN, tmpb);
    ln_relu_res_kernel<<<BN / 4, 256, 0, stream>>>(
        tmpb, gall + (size_t)l * HIDDEN, beall + (size_t)l * HIDDEN,
        xs, out, sorig, N, l > 0, l == NLAYERS - 1);
  }
}